// Round 7
// baseline (812.401 us; speedup 1.0000x reference)
//
#include <hip/hip_runtime.h>
#include <math.h>

#define N_NODES 100000
#define N_EDGES 1600000
#define NBKT    391             // ceil(100000/256) coarse buckets (256 nodes each)
#define BCAP    5120            // per-bucket capacity; mean 4092, +16 sigma

using short8  = __attribute__((ext_vector_type(8))) short;   // 8 bf16 (4 VGPRs)
using float4v = __attribute__((ext_vector_type(4))) float;   // MFMA C/D frag

__device__ inline unsigned short f2bf(float f) {             // fp32 -> bf16 RNE
    unsigned int u = __float_as_uint(f);
    u += 0x7fffu + ((u >> 16) & 1u);
    return (unsigned short)(u >> 16);
}
__device__ inline float bflo(unsigned int v) { return __uint_as_float(v << 16); }
__device__ inline float bfhi(unsigned int v) { return __uint_as_float(v & 0xffff0000u); }

// ---- weight prep (unchanged from R5) ----
__global__ void prep_weights(const float* __restrict__ Wl1, const float* __restrict__ Wr1,
                             const float* __restrict__ Wl2, const float* __restrict__ Wr2,
                             const float* __restrict__ Wc1, const float* __restrict__ Wc2,
                             unsigned short* __restrict__ w1, unsigned short* __restrict__ w2,
                             unsigned short* __restrict__ wcls1, unsigned short* __restrict__ wcls2) {
    int i = blockIdx.x * 256 + threadIdx.x;          // 192*256 = 49152
    if (i < 16384) {
        int n = i >> 7, k = i & 127;
        float v = (k < 64) ? Wl1[k * 128 + n] : Wr1[(k - 64) * 128 + n];
        w1[i] = f2bf(v);
    } else if (i < 32768) {
        int j = i - 16384; int n = j >> 7, k = j & 127;
        float v = (n < 64) ? Wl2[k * 64 + n] : Wr2[k * 64 + (n - 64)];
        w2[j] = f2bf(v);
    } else if (i < 40960) {
        int j = i - 32768; int n = j >> 6, k = j & 63;
        wcls1[j] = f2bf(Wc1[k * 128 + n]);
    } else {
        int j = i - 40960; int n = j >> 7, k = j & 127;
        wcls2[j] = f2bf(Wc2[k * 64 + n]);
    }
}

__global__ void f32_to_bf16x4(const float* __restrict__ src, unsigned short* __restrict__ dst) {
    int i = blockIdx.x * 256 + threadIdx.x;          // 6250*256*4 = 6.4M
    float4 v = *(const float4*)(src + (long)i * 4);
    uint2 o;
    o.x = (unsigned)f2bf(v.x) | ((unsigned)f2bf(v.y) << 16);
    o.y = (unsigned)f2bf(v.z) | ((unsigned)f2bf(v.w) << 16);
    *(uint2*)(dst + (long)i * 4) = o;
}

// ---- binned CSR build ----
// Phase A: bin edges by dst>>8; 391 hot frontier lines stay in L2 -> coalesced writes
__global__ void binA(const int* __restrict__ esrc, const int* __restrict__ edst,
                     int* __restrict__ bcnt, unsigned* __restrict__ stage) {
    int e = blockIdx.x * 256 + threadIdx.x;          // grid exact: 6250*256
    int d = edst[e];
    int s = esrc[e];
    int b = d >> 8;
    int slot = atomicAdd(&bcnt[b], 1);
    if (slot < BCAP)
        stage[(long)b * BCAP + slot] = (unsigned)s | ((unsigned)(d & 255) << 24);
}

// exclusive scan of 391 bucket counts; also seals off[N_NODES]
__global__ void binScan(const int* __restrict__ bcnt, int* __restrict__ bbase,
                        int* __restrict__ off) {
    __shared__ int s[512];
    int t = threadIdx.x;
    int v = (t < NBKT) ? bcnt[t] : 0;
    s[t] = v;
    __syncthreads();
    for (int st = 1; st < 512; st <<= 1) {
        int a = (t >= st) ? s[t - st] : 0;
        __syncthreads();
        s[t] += a;
        __syncthreads();
    }
    if (t < NBKT) bbase[t] = s[t] - v;
    if (t == 0) off[N_NODES] = N_EDGES;
}

// Phase B: one block per bucket. LDS hist -> local prefix -> off[]; LDS-cursor scatter
// into an exclusively-owned ~16KB contiguous bucket[] region (RMW absorbed in L1).
__global__ __launch_bounds__(256) void binB(const int* __restrict__ bcnt,
                                            const int* __restrict__ bbase,
                                            const unsigned* __restrict__ stage,
                                            int* __restrict__ off, int* __restrict__ bucket) {
    __shared__ int hist[256];
    __shared__ int scn[256];
    __shared__ int lbase[256];
    int b = blockIdx.x, t = threadIdx.x;
    int cnt = bcnt[b];
    if (cnt > BCAP) cnt = BCAP;
    int base = bbase[b];
    hist[t] = 0;
    __syncthreads();
    const unsigned* sp = stage + (long)b * BCAP;
    for (int i = t; i < cnt; i += 256) atomicAdd(&hist[sp[i] >> 24], 1);
    __syncthreads();
    int v = hist[t];
    scn[t] = v;
    __syncthreads();
    for (int st = 1; st < 256; st <<= 1) {
        int a = (t >= st) ? scn[t - st] : 0;
        __syncthreads();
        scn[t] += a;
        __syncthreads();
    }
    lbase[t] = scn[t] - v;                 // exclusive local prefix
    int node = b * 256 + t;
    if (node < N_NODES) off[node] = base + lbase[t];
    hist[t] = 0;                           // reuse as running cursor
    __syncthreads();
    for (int i = t; i < cnt; i += 256) {
        unsigned p = sp[i];
        int ln = p >> 24;
        int slot = atomicAdd(&hist[ln], 1);
        bucket[base + lbase[ln] + slot] = (int)(p & 0xFFFFFFu);
    }
}

// ---- bf16 gather: wave per node; lane = (neighbor g = lane>>3, channel octet c8) ----
__global__ __launch_bounds__(256, 8) void gather_b(
        const unsigned short* __restrict__ y, const int* __restrict__ off,
        const int* __restrict__ bucket, unsigned short* __restrict__ outb) {
    int node = __builtin_amdgcn_readfirstlane(blockIdx.x * 4 + (threadIdx.x >> 6));
    int lane = threadIdx.x & 63;
    int g = lane >> 3, c8 = lane & 7;
    int e0 = off[node], e1 = off[node + 1];
    float a[8] = {0.f, 0.f, 0.f, 0.f, 0.f, 0.f, 0.f, 0.f};
    for (int base = e0; base < e1; base += 8) {
        int idx = base + g;
        if (idx < e1) {
            int s = bucket[idx];
            uint4 v = *(const uint4*)(y + (long)s * 64 + c8 * 8);
            a[0] += bflo(v.x); a[1] += bfhi(v.x);
            a[2] += bflo(v.y); a[3] += bfhi(v.y);
            a[4] += bflo(v.z); a[5] += bfhi(v.z);
            a[6] += bflo(v.w); a[7] += bfhi(v.w);
        }
    }
#pragma unroll
    for (int j = 0; j < 8; j++) {
        a[j] += __shfl_xor(a[j], 8);
        a[j] += __shfl_xor(a[j], 16);
        a[j] += __shfl_xor(a[j], 32);
    }
    if (g == 0) {
        float sc = 1.f / fmaxf((float)(e1 - e0), 1.f);
        uint4 o;
        o.x = (unsigned)f2bf(a[0]*sc) | ((unsigned)f2bf(a[1]*sc) << 16);
        o.y = (unsigned)f2bf(a[2]*sc) | ((unsigned)f2bf(a[3]*sc) << 16);
        o.z = (unsigned)f2bf(a[4]*sc) | ((unsigned)f2bf(a[5]*sc) << 16);
        o.w = (unsigned)f2bf(a[6]*sc) | ((unsigned)f2bf(a[7]*sc) << 16);
        *(uint4*)(outb + (long)node * 64 + c8 * 8) = o;
    }
}

__global__ __launch_bounds__(256, 8) void gather_badd(
        const unsigned short* __restrict__ y, const int* __restrict__ off,
        const int* __restrict__ bucket, const float* __restrict__ add,
        float* __restrict__ out) {
    int node = __builtin_amdgcn_readfirstlane(blockIdx.x * 4 + (threadIdx.x >> 6));
    int lane = threadIdx.x & 63;
    int g = lane >> 3, c8 = lane & 7;
    int e0 = off[node], e1 = off[node + 1];
    float a[8] = {0.f, 0.f, 0.f, 0.f, 0.f, 0.f, 0.f, 0.f};
    for (int base = e0; base < e1; base += 8) {
        int idx = base + g;
        if (idx < e1) {
            int s = bucket[idx];
            uint4 v = *(const uint4*)(y + (long)s * 64 + c8 * 8);
            a[0] += bflo(v.x); a[1] += bfhi(v.x);
            a[2] += bflo(v.y); a[3] += bfhi(v.y);
            a[4] += bflo(v.z); a[5] += bfhi(v.z);
            a[6] += bflo(v.w); a[7] += bfhi(v.w);
        }
    }
#pragma unroll
    for (int j = 0; j < 8; j++) {
        a[j] += __shfl_xor(a[j], 8);
        a[j] += __shfl_xor(a[j], 16);
        a[j] += __shfl_xor(a[j], 32);
    }
    if (g == 0) {
        float sc = 1.f / fmaxf((float)(e1 - e0), 1.f);
        const float4* up = (const float4*)(add + (long)node * 64 + c8 * 8);
        float4 u0 = up[0], u1 = up[1];
        float4 r0 = { a[0]*sc + u0.x, a[1]*sc + u0.y, a[2]*sc + u0.z, a[3]*sc + u0.w };
        float4 r1 = { a[4]*sc + u1.x, a[5]*sc + u1.y, a[6]*sc + u1.z, a[7]*sc + u1.w };
        float4* op = (float4*)(out + (long)node * 64 + c8 * 8);
        op[0] = r0; op[1] = r1;
    }
}

// ---- fused conv1 + conv2-transform, bf16 MFMA (unchanged from R5) ----
__global__ __launch_bounds__(256, 4) void fused_conv(
        const unsigned short* __restrict__ xb, const unsigned short* __restrict__ aggb,
        const unsigned short* __restrict__ w1, const float* __restrict__ bl1,
        const unsigned short* __restrict__ w2, const float* __restrict__ bl2,
        unsigned short* __restrict__ t2b, float* __restrict__ u) {
    __shared__ __align__(16) unsigned short smemA[64 * 136];
    __shared__ __align__(16) unsigned short smemH[64 * 136];
    unsigned short* sA = smemA;
    unsigned short* sH = smemH;
    float* su = (float*)smemA;
    unsigned short* st2 = smemH;

    int t = threadIdx.x;
    int lane = t & 63;
    int wv = t >> 6;
    int q = lane >> 4, ln = lane & 15;

    long base = (long)blockIdx.x * 4096;
    long maxe = (long)N_NODES * 64 - 8;
#pragma unroll
    for (int it = 0; it < 2; it++) {
        int i = it * 256 + t;
        int m = i >> 3, k8 = (i & 7) * 8;
        long g = base + (long)m * 64 + k8;
        if (g > maxe) g = maxe;
        *(uint4*)(sA + m * 136 + k8)      = *(const uint4*)(aggb + g);
        *(uint4*)(sA + m * 136 + 64 + k8) = *(const uint4*)(xb + g);
    }
    __syncthreads();

    int n0 = wv * 32;
    float4v acc[2][4];
    {
        float b0 = bl1[n0 + ln], b1 = bl1[n0 + 16 + ln];
#pragma unroll
        for (int mi = 0; mi < 4; mi++) {
            acc[0][mi] = (float4v){b0, b0, b0, b0};
            acc[1][mi] = (float4v){b1, b1, b1, b1};
        }
    }
#pragma unroll
    for (int ks = 0; ks < 4; ks++) {
        int k0 = ks * 32 + q * 8;
        short8 bf0 = *(const short8*)(w1 + (long)(n0 + ln) * 128 + k0);
        short8 bf1 = *(const short8*)(w1 + (long)(n0 + 16 + ln) * 128 + k0);
#pragma unroll
        for (int mi = 0; mi < 4; mi++) {
            short8 af = *(const short8*)(sA + (mi * 16 + ln) * 136 + k0);
            acc[0][mi] = __builtin_amdgcn_mfma_f32_16x16x32_bf16(af, bf0, acc[0][mi], 0, 0, 0);
            acc[1][mi] = __builtin_amdgcn_mfma_f32_16x16x32_bf16(af, bf1, acc[1][mi], 0, 0, 0);
        }
    }
#pragma unroll
    for (int j = 0; j < 2; j++)
#pragma unroll
        for (int mi = 0; mi < 4; mi++) {
            int n = n0 + j * 16 + ln;
#pragma unroll
            for (int r = 0; r < 4; r++) {
                int m = mi * 16 + q * 4 + r;
                sH[m * 136 + n] = f2bf(fmaxf(acc[j][mi][r], 0.f));
            }
        }
    __syncthreads();

    float4v acc2[2][4];
    {
        float c0 = (n0 >= 64) ? bl2[n0 - 64 + ln] : 0.f;
        float c1 = (n0 >= 64) ? bl2[n0 - 48 + ln] : 0.f;
#pragma unroll
        for (int mi = 0; mi < 4; mi++) {
            acc2[0][mi] = (float4v){c0, c0, c0, c0};
            acc2[1][mi] = (float4v){c1, c1, c1, c1};
        }
    }
#pragma unroll
    for (int ks = 0; ks < 4; ks++) {
        int k0 = ks * 32 + q * 8;
        short8 bf0 = *(const short8*)(w2 + (long)(n0 + ln) * 128 + k0);
        short8 bf1 = *(const short8*)(w2 + (long)(n0 + 16 + ln) * 128 + k0);
#pragma unroll
        for (int mi = 0; mi < 4; mi++) {
            short8 af = *(const short8*)(sH + (mi * 16 + ln) * 136 + k0);
            acc2[0][mi] = __builtin_amdgcn_mfma_f32_16x16x32_bf16(af, bf0, acc2[0][mi], 0, 0, 0);
            acc2[1][mi] = __builtin_amdgcn_mfma_f32_16x16x32_bf16(af, bf1, acc2[1][mi], 0, 0, 0);
        }
    }
    __syncthreads();

#pragma unroll
    for (int j = 0; j < 2; j++)
#pragma unroll
        for (int mi = 0; mi < 4; mi++) {
            int n = n0 + j * 16 + ln;
#pragma unroll
            for (int r = 0; r < 4; r++) {
                int m = mi * 16 + q * 4 + r;
                if (wv < 2) st2[m * 72 + n] = f2bf(acc2[j][mi][r]);
                else        su[m * 68 + (n - 64)] = acc2[j][mi][r];
            }
        }
    __syncthreads();

    long lim = (long)N_NODES * 64;
    unsigned int* t2u = (unsigned int*)(t2b + base);
#pragma unroll
    for (int it = 0; it < 8; it++) {
        int i = it * 256 + t;
        long g = base + (long)i * 2;
        if (g + 1 < lim) {
            int m = (i * 2) >> 6, n = (i * 2) & 63;
            t2u[i] = (unsigned)st2[m * 72 + n] | ((unsigned)st2[m * 72 + n + 1] << 16);
        }
    }
#pragma unroll
    for (int it = 0; it < 16; it++) {
        int i = it * 256 + t;
        long g = base + i;
        if (g < lim) u[g] = su[(i >> 6) * 68 + (i & 63)];
    }
}

// ---- fused classifier head, bf16 MFMA (unchanged from R5) ----
__global__ __launch_bounds__(256, 4) void fused_cls(
        const float* __restrict__ emb,
        const unsigned short* __restrict__ wcls1, const float* __restrict__ bc1,
        const unsigned short* __restrict__ wcls2, const float* __restrict__ bc2,
        const float* __restrict__ wc3, const float* __restrict__ bc3,
        float* __restrict__ probs) {
    __shared__ __align__(16) unsigned short smem[64 * 136];
    __shared__ float psum[4][64];
    unsigned short* sE = smem;
    unsigned short* sC = smem;

    int t = threadIdx.x;
    int wv = t >> 6;
    int lane = t & 63;
    int q = lane >> 4, ln = lane & 15;

    long base = (long)blockIdx.x * 4096;
    long maxe = (long)N_NODES * 64 - 4;
#pragma unroll
    for (int it = 0; it < 4; it++) {
        int i = it * 256 + t;
        int m = i >> 4, k4 = (i & 15) * 4;
        long g = base + (long)m * 64 + k4;
        if (g > maxe) g = maxe;
        float4 v = *(const float4*)(emb + g);
        uint2 o;
        o.x = (unsigned)f2bf(v.x) | ((unsigned)f2bf(v.y) << 16);
        o.y = (unsigned)f2bf(v.z) | ((unsigned)f2bf(v.w) << 16);
        *(uint2*)(sE + m * 72 + k4) = o;
    }
    __syncthreads();

    int n0 = wv * 32;
    float4v acc[2][4];
    {
        float b0 = bc1[n0 + ln], b1 = bc1[n0 + 16 + ln];
#pragma unroll
        for (int mi = 0; mi < 4; mi++) {
            acc[0][mi] = (float4v){b0, b0, b0, b0};
            acc[1][mi] = (float4v){b1, b1, b1, b1};
        }
    }
#pragma unroll
    for (int ks = 0; ks < 2; ks++) {
        int k0 = ks * 32 + q * 8;
        short8 bf0 = *(const short8*)(wcls1 + (long)(n0 + ln) * 64 + k0);
        short8 bf1 = *(const short8*)(wcls1 + (long)(n0 + 16 + ln) * 64 + k0);
#pragma unroll
        for (int mi = 0; mi < 4; mi++) {
            short8 af = *(const short8*)(sE + (mi * 16 + ln) * 72 + k0);
            acc[0][mi] = __builtin_amdgcn_mfma_f32_16x16x32_bf16(af, bf0, acc[0][mi], 0, 0, 0);
            acc[1][mi] = __builtin_amdgcn_mfma_f32_16x16x32_bf16(af, bf1, acc[1][mi], 0, 0, 0);
        }
    }
    __syncthreads();
#pragma unroll
    for (int j = 0; j < 2; j++)
#pragma unroll
        for (int mi = 0; mi < 4; mi++) {
            int n = n0 + j * 16 + ln;
#pragma unroll
            for (int r = 0; r < 4; r++) {
                int m = mi * 16 + q * 4 + r;
                sC[m * 136 + n] = f2bf(fmaxf(acc[j][mi][r], 0.f));
            }
        }
    __syncthreads();

    int n0c = wv * 16;
    float4v acc3[4];
    {
        float b = bc2[n0c + ln];
#pragma unroll
        for (int mi = 0; mi < 4; mi++) acc3[mi] = (float4v){b, b, b, b};
    }
#pragma unroll
    for (int ks = 0; ks < 4; ks++) {
        int k0 = ks * 32 + q * 8;
        short8 bf0 = *(const short8*)(wcls2 + (long)(n0c + ln) * 128 + k0);
#pragma unroll
        for (int mi = 0; mi < 4; mi++) {
            short8 af = *(const short8*)(sC + (mi * 16 + ln) * 136 + k0);
            acc3[mi] = __builtin_amdgcn_mfma_f32_16x16x32_bf16(af, bf0, acc3[mi], 0, 0, 0);
        }
    }
    float w3 = wc3[n0c + ln];
#pragma unroll
    for (int mi = 0; mi < 4; mi++)
#pragma unroll
        for (int r = 0; r < 4; r++) {
            float v = fmaxf(acc3[mi][r], 0.f) * w3;
            v += __shfl_xor(v, 1);
            v += __shfl_xor(v, 2);
            v += __shfl_xor(v, 4);
            v += __shfl_xor(v, 8);
            if (ln == 0) psum[wv][mi * 16 + q * 4 + r] = v;
        }
    __syncthreads();
    if (t < 64) {
        int node = blockIdx.x * 64 + t;
        if (node < N_NODES) {
            float tot = psum[0][t] + psum[1][t] + psum[2][t] + psum[3][t] + bc3[0];
            probs[node] = 1.f / (1.f + expf(-tot));
        }
    }
}

extern "C" void kernel_launch(void* const* d_in, const int* in_sizes, int n_in,
                              void* d_out, int out_size, void* d_ws, size_t ws_size,
                              hipStream_t stream) {
    const float* x   = (const float*)d_in[0];
    const int*   ei  = (const int*)d_in[1];
    const float* Wl1 = (const float*)d_in[2];
    const float* bl1 = (const float*)d_in[3];
    const float* Wr1 = (const float*)d_in[4];
    const float* Wl2 = (const float*)d_in[5];
    const float* bl2 = (const float*)d_in[6];
    const float* Wr2 = (const float*)d_in[7];
    const float* Wc1 = (const float*)d_in[8];
    const float* bc1 = (const float*)d_in[9];
    const float* Wc2 = (const float*)d_in[10];
    const float* bc2 = (const float*)d_in[11];
    const float* Wc3 = (const float*)d_in[12];
    const float* bc3 = (const float*)d_in[13];

    float* out = (float*)d_out;

    // ---- ws carve ----
    int* iw     = (int*)d_ws;
    int* bcnt   = iw;                       // 392 (zeroed)
    int* bbase  = iw + 392;                 // 392 (+pad to 1024 total)
    int* off    = iw + 1024;                // N_NODES+1, padded to 100352
    int* bucket = iw + 1024 + 100352;       // N_EDGES
    unsigned* stage = (unsigned*)(iw + 1024 + 100352 + N_EDGES);  // NBKT*BCAP
    size_t ioff = (size_t)(1024 + 100352 + N_EDGES + (long)NBKT * BCAP) * 4;

    char* wsb = (char*)d_ws;
    unsigned short* xb    = (unsigned short*)(wsb + ioff);                  // 12.8 MB
    unsigned short* agg1b = xb + 6400000L;                                  // 12.8 MB
    unsigned short* t2b   = agg1b + 6400000L;                               // 12.8 MB
    float*          u     = (float*)(wsb + ioff + 3L * 12800000L);          // 25.6 MB
    unsigned short* w1    = (unsigned short*)(wsb + ioff + 3L * 12800000L + 25600000L);
    unsigned short* w2    = w1 + 16384;
    unsigned short* wcls1 = w2 + 16384;
    unsigned short* wcls2 = wcls1 + 8192;

    float* emb   = out;                     // [100000 x 64]
    float* probs = out + 6400000L;          // [100000]

    const int* esrc = ei;
    const int* edst = ei + N_EDGES;

    hipMemsetAsync(bcnt, 0, 1024 * sizeof(int), stream);

    prep_weights<<<192, 256, 0, stream>>>(Wl1, Wr1, Wl2, Wr2, Wc1, Wc2,
                                          w1, w2, wcls1, wcls2);
    f32_to_bf16x4<<<6250, 256, 0, stream>>>(x, xb);

    binA<<<6250, 256, 0, stream>>>(esrc, edst, bcnt, stage);
    binScan<<<1, 512, 0, stream>>>(bcnt, bbase, off);
    binB<<<NBKT, 256, 0, stream>>>(bcnt, bbase, stage, off, bucket);

    gather_b<<<25000, 256, 0, stream>>>(xb, off, bucket, agg1b);
    fused_conv<<<1563, 256, 0, stream>>>(xb, agg1b, w1, bl1, w2, bl2, t2b, u);
    gather_badd<<<25000, 256, 0, stream>>>(t2b, off, bucket, u, emb);
    fused_cls<<<1563, 256, 0, stream>>>(emb, wcls1, bc1, wcls2, bc2, Wc3, bc3, probs);
}

// Round 8
// 283.952 us; speedup vs baseline: 2.8611x; 2.8611x over previous
//
#include <hip/hip_runtime.h>
#include <math.h>

#define N_NODES 100000
#define N_EDGES 1600000
#define NBKT    391             // ceil(100000/256) coarse buckets (256 nodes each)
#define BCAP    5120            // per-bucket capacity; mean 4092, +16 sigma
#define EPB     4096            // edges per binA block
#define NBLKA   391             // ceil(N_EDGES/EPB)

using short8  = __attribute__((ext_vector_type(8))) short;   // 8 bf16 (4 VGPRs)
using float4v = __attribute__((ext_vector_type(4))) float;   // MFMA C/D frag

__device__ inline unsigned short f2bf(float f) {             // fp32 -> bf16 RNE
    unsigned int u = __float_as_uint(f);
    u += 0x7fffu + ((u >> 16) & 1u);
    return (unsigned short)(u >> 16);
}
__device__ inline float bflo(unsigned int v) { return __uint_as_float(v << 16); }
__device__ inline float bfhi(unsigned int v) { return __uint_as_float(v & 0xffff0000u); }

// ---- weight prep ----
__global__ void prep_weights(const float* __restrict__ Wl1, const float* __restrict__ Wr1,
                             const float* __restrict__ Wl2, const float* __restrict__ Wr2,
                             const float* __restrict__ Wc1, const float* __restrict__ Wc2,
                             unsigned short* __restrict__ w1, unsigned short* __restrict__ w2,
                             unsigned short* __restrict__ wcls1, unsigned short* __restrict__ wcls2) {
    int i = blockIdx.x * 256 + threadIdx.x;          // 192*256 = 49152
    if (i < 16384) {
        int n = i >> 7, k = i & 127;
        float v = (k < 64) ? Wl1[k * 128 + n] : Wr1[(k - 64) * 128 + n];
        w1[i] = f2bf(v);
    } else if (i < 32768) {
        int j = i - 16384; int n = j >> 7, k = j & 127;
        float v = (n < 64) ? Wl2[k * 64 + n] : Wr2[k * 64 + (n - 64)];
        w2[j] = f2bf(v);
    } else if (i < 40960) {
        int j = i - 32768; int n = j >> 6, k = j & 63;
        wcls1[j] = f2bf(Wc1[k * 128 + n]);
    } else {
        int j = i - 40960; int n = j >> 7, k = j & 127;
        wcls2[j] = f2bf(Wc2[k * 64 + n]);
    }
}

__global__ void f32_to_bf16x4(const float* __restrict__ src, unsigned short* __restrict__ dst) {
    int i = blockIdx.x * 256 + threadIdx.x;          // 6250*256*4 = 6.4M
    float4 v = *(const float4*)(src + (long)i * 4);
    uint2 o;
    o.x = (unsigned)f2bf(v.x) | ((unsigned)f2bf(v.y) << 16);
    o.y = (unsigned)f2bf(v.z) | ((unsigned)f2bf(v.w) << 16);
    *(uint2*)(dst + (long)i * 4) = o;
}

// ---- binned CSR build ----
// Phase A: LDS histogram per 4096-edge block; ONE global atomic per (block,bucket)
// to reserve a contiguous range; LDS-cursor scatter into stage.
__global__ __launch_bounds__(256) void binA(const int* __restrict__ esrc,
                                            const int* __restrict__ edst,
                                            int* __restrict__ bcnt,
                                            unsigned* __restrict__ stage) {
    __shared__ int hist[NBKT];
    __shared__ int rbase[NBKT];
    int t = threadIdx.x;
    for (int i = t; i < NBKT; i += 256) hist[i] = 0;
    __syncthreads();
    int e0 = blockIdx.x * EPB;
    int e1 = e0 + EPB; if (e1 > N_EDGES) e1 = N_EDGES;
    for (int e = e0 + t; e < e1; e += 256)
        atomicAdd(&hist[edst[e] >> 8], 1);
    __syncthreads();
    for (int i = t; i < NBKT; i += 256) {
        int c = hist[i];
        rbase[i] = c ? atomicAdd(&bcnt[i], c) : 0;
        hist[i] = 0;                       // becomes cursor
    }
    __syncthreads();
    for (int e = e0 + t; e < e1; e += 256) {
        int d = edst[e];
        int s = esrc[e];
        int b = d >> 8;
        int slot = rbase[b] + atomicAdd(&hist[b], 1);
        if (slot < BCAP)
            stage[(long)b * BCAP + slot] = (unsigned)s | ((unsigned)(d & 255) << 24);
    }
}

// exclusive scan of 391 bucket counts; also seals off[N_NODES]
__global__ void binScan(const int* __restrict__ bcnt, int* __restrict__ bbase,
                        int* __restrict__ off) {
    __shared__ int s[512];
    int t = threadIdx.x;
    int v = (t < NBKT) ? bcnt[t] : 0;
    s[t] = v;
    __syncthreads();
    for (int st = 1; st < 512; st <<= 1) {
        int a = (t >= st) ? s[t - st] : 0;
        __syncthreads();
        s[t] += a;
        __syncthreads();
    }
    if (t < NBKT) bbase[t] = s[t] - v;
    if (t == 0) off[N_NODES] = N_EDGES;
}

// Phase B: one block per bucket. LDS hist -> local prefix -> off[]; LDS-cursor scatter
// into an exclusively-owned ~16KB contiguous bucket[] region (RMW absorbed in L1/L2).
__global__ __launch_bounds__(256) void binB(const int* __restrict__ bcnt,
                                            const int* __restrict__ bbase,
                                            const unsigned* __restrict__ stage,
                                            int* __restrict__ off, int* __restrict__ bucket) {
    __shared__ int hist[256];
    __shared__ int scn[256];
    __shared__ int lbase[256];
    int b = blockIdx.x, t = threadIdx.x;
    int cnt = bcnt[b];
    if (cnt > BCAP) cnt = BCAP;
    int base = bbase[b];
    hist[t] = 0;
    __syncthreads();
    const unsigned* sp = stage + (long)b * BCAP;
    for (int i = t; i < cnt; i += 256) atomicAdd(&hist[sp[i] >> 24], 1);
    __syncthreads();
    int v = hist[t];
    scn[t] = v;
    __syncthreads();
    for (int st = 1; st < 256; st <<= 1) {
        int a = (t >= st) ? scn[t - st] : 0;
        __syncthreads();
        scn[t] += a;
        __syncthreads();
    }
    lbase[t] = scn[t] - v;
    int node = b * 256 + t;
    if (node < N_NODES) off[node] = base + lbase[t];
    hist[t] = 0;                           // reuse as running cursor
    __syncthreads();
    for (int i = t; i < cnt; i += 256) {
        unsigned p = sp[i];
        int ln = p >> 24;
        int slot = atomicAdd(&hist[ln], 1);
        bucket[base + lbase[ln] + slot] = (int)(p & 0xFFFFFFu);
    }
}

// ---- bf16 gather: wave per node; lane = (neighbor g = lane>>3, channel octet c8) ----
__global__ __launch_bounds__(256, 8) void gather_b(
        const unsigned short* __restrict__ y, const int* __restrict__ off,
        const int* __restrict__ bucket, unsigned short* __restrict__ outb) {
    int node = __builtin_amdgcn_readfirstlane(blockIdx.x * 4 + (threadIdx.x >> 6));
    int lane = threadIdx.x & 63;
    int g = lane >> 3, c8 = lane & 7;
    int e0 = off[node], e1 = off[node + 1];
    float a[8] = {0.f, 0.f, 0.f, 0.f, 0.f, 0.f, 0.f, 0.f};
    for (int base = e0; base < e1; base += 8) {
        int idx = base + g;
        if (idx < e1) {
            int s = bucket[idx];
            uint4 v = *(const uint4*)(y + (long)s * 64 + c8 * 8);
            a[0] += bflo(v.x); a[1] += bfhi(v.x);
            a[2] += bflo(v.y); a[3] += bfhi(v.y);
            a[4] += bflo(v.z); a[5] += bfhi(v.z);
            a[6] += bflo(v.w); a[7] += bfhi(v.w);
        }
    }
#pragma unroll
    for (int j = 0; j < 8; j++) {
        a[j] += __shfl_xor(a[j], 8);
        a[j] += __shfl_xor(a[j], 16);
        a[j] += __shfl_xor(a[j], 32);
    }
    if (g == 0) {
        float sc = 1.f / fmaxf((float)(e1 - e0), 1.f);
        uint4 o;
        o.x = (unsigned)f2bf(a[0]*sc) | ((unsigned)f2bf(a[1]*sc) << 16);
        o.y = (unsigned)f2bf(a[2]*sc) | ((unsigned)f2bf(a[3]*sc) << 16);
        o.z = (unsigned)f2bf(a[4]*sc) | ((unsigned)f2bf(a[5]*sc) << 16);
        o.w = (unsigned)f2bf(a[6]*sc) | ((unsigned)f2bf(a[7]*sc) << 16);
        *(uint4*)(outb + (long)node * 64 + c8 * 8) = o;
    }
}

__global__ __launch_bounds__(256, 8) void gather_badd(
        const unsigned short* __restrict__ y, const int* __restrict__ off,
        const int* __restrict__ bucket, const float* __restrict__ add,
        float* __restrict__ out) {
    int node = __builtin_amdgcn_readfirstlane(blockIdx.x * 4 + (threadIdx.x >> 6));
    int lane = threadIdx.x & 63;
    int g = lane >> 3, c8 = lane & 7;
    int e0 = off[node], e1 = off[node + 1];
    float a[8] = {0.f, 0.f, 0.f, 0.f, 0.f, 0.f, 0.f, 0.f};
    for (int base = e0; base < e1; base += 8) {
        int idx = base + g;
        if (idx < e1) {
            int s = bucket[idx];
            uint4 v = *(const uint4*)(y + (long)s * 64 + c8 * 8);
            a[0] += bflo(v.x); a[1] += bfhi(v.x);
            a[2] += bflo(v.y); a[3] += bfhi(v.y);
            a[4] += bflo(v.z); a[5] += bfhi(v.z);
            a[6] += bflo(v.w); a[7] += bfhi(v.w);
        }
    }
#pragma unroll
    for (int j = 0; j < 8; j++) {
        a[j] += __shfl_xor(a[j], 8);
        a[j] += __shfl_xor(a[j], 16);
        a[j] += __shfl_xor(a[j], 32);
    }
    if (g == 0) {
        float sc = 1.f / fmaxf((float)(e1 - e0), 1.f);
        const float4* up = (const float4*)(add + (long)node * 64 + c8 * 8);
        float4 u0 = up[0], u1 = up[1];
        float4 r0 = { a[0]*sc + u0.x, a[1]*sc + u0.y, a[2]*sc + u0.z, a[3]*sc + u0.w };
        float4 r1 = { a[4]*sc + u1.x, a[5]*sc + u1.y, a[6]*sc + u1.z, a[7]*sc + u1.w };
        float4* op = (float4*)(out + (long)node * 64 + c8 * 8);
        op[0] = r0; op[1] = r1;
    }
}

// ---- fused conv1 + conv2-transform, bf16 MFMA ----
__global__ __launch_bounds__(256, 4) void fused_conv(
        const unsigned short* __restrict__ xb, const unsigned short* __restrict__ aggb,
        const unsigned short* __restrict__ w1, const float* __restrict__ bl1,
        const unsigned short* __restrict__ w2, const float* __restrict__ bl2,
        unsigned short* __restrict__ t2b, float* __restrict__ u) {
    __shared__ __align__(16) unsigned short smemA[64 * 136];
    __shared__ __align__(16) unsigned short smemH[64 * 136];
    unsigned short* sA = smemA;
    unsigned short* sH = smemH;
    float* su = (float*)smemA;
    unsigned short* st2 = smemH;

    int t = threadIdx.x;
    int lane = t & 63;
    int wv = t >> 6;
    int q = lane >> 4, ln = lane & 15;

    long base = (long)blockIdx.x * 4096;
    long maxe = (long)N_NODES * 64 - 8;
#pragma unroll
    for (int it = 0; it < 2; it++) {
        int i = it * 256 + t;
        int m = i >> 3, k8 = (i & 7) * 8;
        long g = base + (long)m * 64 + k8;
        if (g > maxe) g = maxe;
        *(uint4*)(sA + m * 136 + k8)      = *(const uint4*)(aggb + g);
        *(uint4*)(sA + m * 136 + 64 + k8) = *(const uint4*)(xb + g);
    }
    __syncthreads();

    int n0 = wv * 32;
    float4v acc[2][4];
    {
        float b0 = bl1[n0 + ln], b1 = bl1[n0 + 16 + ln];
#pragma unroll
        for (int mi = 0; mi < 4; mi++) {
            acc[0][mi] = (float4v){b0, b0, b0, b0};
            acc[1][mi] = (float4v){b1, b1, b1, b1};
        }
    }
#pragma unroll
    for (int ks = 0; ks < 4; ks++) {
        int k0 = ks * 32 + q * 8;
        short8 bf0 = *(const short8*)(w1 + (long)(n0 + ln) * 128 + k0);
        short8 bf1 = *(const short8*)(w1 + (long)(n0 + 16 + ln) * 128 + k0);
#pragma unroll
        for (int mi = 0; mi < 4; mi++) {
            short8 af = *(const short8*)(sA + (mi * 16 + ln) * 136 + k0);
            acc[0][mi] = __builtin_amdgcn_mfma_f32_16x16x32_bf16(af, bf0, acc[0][mi], 0, 0, 0);
            acc[1][mi] = __builtin_amdgcn_mfma_f32_16x16x32_bf16(af, bf1, acc[1][mi], 0, 0, 0);
        }
    }
#pragma unroll
    for (int j = 0; j < 2; j++)
#pragma unroll
        for (int mi = 0; mi < 4; mi++) {
            int n = n0 + j * 16 + ln;
#pragma unroll
            for (int r = 0; r < 4; r++) {
                int m = mi * 16 + q * 4 + r;
                sH[m * 136 + n] = f2bf(fmaxf(acc[j][mi][r], 0.f));
            }
        }
    __syncthreads();

    float4v acc2[2][4];
    {
        float c0 = (n0 >= 64) ? bl2[n0 - 64 + ln] : 0.f;
        float c1 = (n0 >= 64) ? bl2[n0 - 48 + ln] : 0.f;
#pragma unroll
        for (int mi = 0; mi < 4; mi++) {
            acc2[0][mi] = (float4v){c0, c0, c0, c0};
            acc2[1][mi] = (float4v){c1, c1, c1, c1};
        }
    }
#pragma unroll
    for (int ks = 0; ks < 4; ks++) {
        int k0 = ks * 32 + q * 8;
        short8 bf0 = *(const short8*)(w2 + (long)(n0 + ln) * 128 + k0);
        short8 bf1 = *(const short8*)(w2 + (long)(n0 + 16 + ln) * 128 + k0);
#pragma unroll
        for (int mi = 0; mi < 4; mi++) {
            short8 af = *(const short8*)(sH + (mi * 16 + ln) * 136 + k0);
            acc2[0][mi] = __builtin_amdgcn_mfma_f32_16x16x32_bf16(af, bf0, acc2[0][mi], 0, 0, 0);
            acc2[1][mi] = __builtin_amdgcn_mfma_f32_16x16x32_bf16(af, bf1, acc2[1][mi], 0, 0, 0);
        }
    }
    __syncthreads();

#pragma unroll
    for (int j = 0; j < 2; j++)
#pragma unroll
        for (int mi = 0; mi < 4; mi++) {
            int n = n0 + j * 16 + ln;
#pragma unroll
            for (int r = 0; r < 4; r++) {
                int m = mi * 16 + q * 4 + r;
                if (wv < 2) st2[m * 72 + n] = f2bf(acc2[j][mi][r]);
                else        su[m * 68 + (n - 64)] = acc2[j][mi][r];
            }
        }
    __syncthreads();

    long lim = (long)N_NODES * 64;
    unsigned int* t2u = (unsigned int*)(t2b + base);
#pragma unroll
    for (int it = 0; it < 8; it++) {
        int i = it * 256 + t;
        long g = base + (long)i * 2;
        if (g + 1 < lim) {
            int m = (i * 2) >> 6, n = (i * 2) & 63;
            t2u[i] = (unsigned)st2[m * 72 + n] | ((unsigned)st2[m * 72 + n + 1] << 16);
        }
    }
#pragma unroll
    for (int it = 0; it < 16; it++) {
        int i = it * 256 + t;
        long g = base + i;
        if (g < lim) u[g] = su[(i >> 6) * 68 + (i & 63)];
    }
}

// ---- fused classifier head, bf16 MFMA ----
__global__ __launch_bounds__(256, 4) void fused_cls(
        const float* __restrict__ emb,
        const unsigned short* __restrict__ wcls1, const float* __restrict__ bc1,
        const unsigned short* __restrict__ wcls2, const float* __restrict__ bc2,
        const float* __restrict__ wc3, const float* __restrict__ bc3,
        float* __restrict__ probs) {
    __shared__ __align__(16) unsigned short smem[64 * 136];
    __shared__ float psum[4][64];
    unsigned short* sE = smem;
    unsigned short* sC = smem;

    int t = threadIdx.x;
    int wv = t >> 6;
    int lane = t & 63;
    int q = lane >> 4, ln = lane & 15;

    long base = (long)blockIdx.x * 4096;
    long maxe = (long)N_NODES * 64 - 4;
#pragma unroll
    for (int it = 0; it < 4; it++) {
        int i = it * 256 + t;
        int m = i >> 4, k4 = (i & 15) * 4;
        long g = base + (long)m * 64 + k4;
        if (g > maxe) g = maxe;
        float4 v = *(const float4*)(emb + g);
        uint2 o;
        o.x = (unsigned)f2bf(v.x) | ((unsigned)f2bf(v.y) << 16);
        o.y = (unsigned)f2bf(v.z) | ((unsigned)f2bf(v.w) << 16);
        *(uint2*)(sE + m * 72 + k4) = o;
    }
    __syncthreads();

    int n0 = wv * 32;
    float4v acc[2][4];
    {
        float b0 = bc1[n0 + ln], b1 = bc1[n0 + 16 + ln];
#pragma unroll
        for (int mi = 0; mi < 4; mi++) {
            acc[0][mi] = (float4v){b0, b0, b0, b0};
            acc[1][mi] = (float4v){b1, b1, b1, b1};
        }
    }
#pragma unroll
    for (int ks = 0; ks < 2; ks++) {
        int k0 = ks * 32 + q * 8;
        short8 bf0 = *(const short8*)(wcls1 + (long)(n0 + ln) * 64 + k0);
        short8 bf1 = *(const short8*)(wcls1 + (long)(n0 + 16 + ln) * 64 + k0);
#pragma unroll
        for (int mi = 0; mi < 4; mi++) {
            short8 af = *(const short8*)(sE + (mi * 16 + ln) * 72 + k0);
            acc[0][mi] = __builtin_amdgcn_mfma_f32_16x16x32_bf16(af, bf0, acc[0][mi], 0, 0, 0);
            acc[1][mi] = __builtin_amdgcn_mfma_f32_16x16x32_bf16(af, bf1, acc[1][mi], 0, 0, 0);
        }
    }
    __syncthreads();
#pragma unroll
    for (int j = 0; j < 2; j++)
#pragma unroll
        for (int mi = 0; mi < 4; mi++) {
            int n = n0 + j * 16 + ln;
#pragma unroll
            for (int r = 0; r < 4; r++) {
                int m = mi * 16 + q * 4 + r;
                sC[m * 136 + n] = f2bf(fmaxf(acc[j][mi][r], 0.f));
            }
        }
    __syncthreads();

    int n0c = wv * 16;
    float4v acc3[4];
    {
        float b = bc2[n0c + ln];
#pragma unroll
        for (int mi = 0; mi < 4; mi++) acc3[mi] = (float4v){b, b, b, b};
    }
#pragma unroll
    for (int ks = 0; ks < 4; ks++) {
        int k0 = ks * 32 + q * 8;
        short8 bf0 = *(const short8*)(wcls2 + (long)(n0c + ln) * 128 + k0);
#pragma unroll
        for (int mi = 0; mi < 4; mi++) {
            short8 af = *(const short8*)(sC + (mi * 16 + ln) * 136 + k0);
            acc3[mi] = __builtin_amdgcn_mfma_f32_16x16x32_bf16(af, bf0, acc3[mi], 0, 0, 0);
        }
    }
    float w3 = wc3[n0c + ln];
#pragma unroll
    for (int mi = 0; mi < 4; mi++)
#pragma unroll
        for (int r = 0; r < 4; r++) {
            float v = fmaxf(acc3[mi][r], 0.f) * w3;
            v += __shfl_xor(v, 1);
            v += __shfl_xor(v, 2);
            v += __shfl_xor(v, 4);
            v += __shfl_xor(v, 8);
            if (ln == 0) psum[wv][mi * 16 + q * 4 + r] = v;
        }
    __syncthreads();
    if (t < 64) {
        int node = blockIdx.x * 64 + t;
        if (node < N_NODES) {
            float tot = psum[0][t] + psum[1][t] + psum[2][t] + psum[3][t] + bc3[0];
            probs[node] = 1.f / (1.f + expf(-tot));
        }
    }
}

extern "C" void kernel_launch(void* const* d_in, const int* in_sizes, int n_in,
                              void* d_out, int out_size, void* d_ws, size_t ws_size,
                              hipStream_t stream) {
    const float* x   = (const float*)d_in[0];
    const int*   ei  = (const int*)d_in[1];
    const float* Wl1 = (const float*)d_in[2];
    const float* bl1 = (const float*)d_in[3];
    const float* Wr1 = (const float*)d_in[4];
    const float* Wl2 = (const float*)d_in[5];
    const float* bl2 = (const float*)d_in[6];
    const float* Wr2 = (const float*)d_in[7];
    const float* Wc1 = (const float*)d_in[8];
    const float* bc1 = (const float*)d_in[9];
    const float* Wc2 = (const float*)d_in[10];
    const float* bc2 = (const float*)d_in[11];
    const float* Wc3 = (const float*)d_in[12];
    const float* bc3 = (const float*)d_in[13];

    float* out = (float*)d_out;

    // ---- ws carve ----
    int* iw     = (int*)d_ws;
    int* bcnt   = iw;                       // 392 (zeroed)
    int* bbase  = iw + 392;                 // 392 (+pad to 1024 total)
    int* off    = iw + 1024;                // N_NODES+1, padded to 100352
    int* bucket = iw + 1024 + 100352;       // N_EDGES
    unsigned* stage = (unsigned*)(iw + 1024 + 100352 + N_EDGES);  // NBKT*BCAP
    size_t ioff = (size_t)(1024 + 100352 + N_EDGES + (long)NBKT * BCAP) * 4;

    char* wsb = (char*)d_ws;
    unsigned short* xb    = (unsigned short*)(wsb + ioff);                  // 12.8 MB
    unsigned short* agg1b = xb + 6400000L;                                  // 12.8 MB
    unsigned short* t2b   = agg1b + 6400000L;                               // 12.8 MB
    float*          u     = (float*)(wsb + ioff + 3L * 12800000L);          // 25.6 MB
    unsigned short* w1    = (unsigned short*)(wsb + ioff + 3L * 12800000L + 25600000L);
    unsigned short* w2    = w1 + 16384;
    unsigned short* wcls1 = w2 + 16384;
    unsigned short* wcls2 = wcls1 + 8192;

    float* emb   = out;                     // [100000 x 64]
    float* probs = out + 6400000L;          // [100000]

    const int* esrc = ei;
    const int* edst = ei + N_EDGES;

    hipMemsetAsync(bcnt, 0, 1024 * sizeof(int), stream);

    prep_weights<<<192, 256, 0, stream>>>(Wl1, Wr1, Wl2, Wr2, Wc1, Wc2,
                                          w1, w2, wcls1, wcls2);
    f32_to_bf16x4<<<6250, 256, 0, stream>>>(x, xb);

    binA<<<NBLKA, 256, 0, stream>>>(esrc, edst, bcnt, stage);
    binScan<<<1, 512, 0, stream>>>(bcnt, bbase, off);
    binB<<<NBKT, 256, 0, stream>>>(bcnt, bbase, stage, off, bucket);

    gather_b<<<25000, 256, 0, stream>>>(xb, off, bucket, agg1b);
    fused_conv<<<1563, 256, 0, stream>>>(xb, agg1b, w1, bl1, w2, bl2, t2b, u);
    gather_badd<<<25000, 256, 0, stream>>>(t2b, off, bucket, u, emb);
    fused_cls<<<1563, 256, 0, stream>>>(emb, wcls1, bc1, wcls2, bc2, Wc3, bc3, probs);
}

// Round 9
// 269.627 us; speedup vs baseline: 3.0130x; 1.0531x over previous
//
#include <hip/hip_runtime.h>
#include <math.h>

#define N_NODES 100000
#define N_EDGES 1600000
#define NBKT    391             // ceil(100000/256) coarse buckets (256 nodes each)
#define BCAP    5120            // per-bucket capacity; mean 4092, +16 sigma
#define EPB     4096            // edges per binA block
#define NBLKA   391             // ceil(N_EDGES/EPB)

using short8  = __attribute__((ext_vector_type(8))) short;   // 8 bf16 (4 VGPRs)
using float4v = __attribute__((ext_vector_type(4))) float;   // MFMA C/D frag

__device__ inline unsigned short f2bf(float f) {             // fp32 -> bf16 RNE
    unsigned int u = __float_as_uint(f);
    u += 0x7fffu + ((u >> 16) & 1u);
    return (unsigned short)(u >> 16);
}
__device__ inline float bflo(unsigned int v) { return __uint_as_float(v << 16); }
__device__ inline float bfhi(unsigned int v) { return __uint_as_float(v & 0xffff0000u); }

// ---- weight prep ----
__global__ void prep_weights(const float* __restrict__ Wl1, const float* __restrict__ Wr1,
                             const float* __restrict__ Wl2, const float* __restrict__ Wr2,
                             const float* __restrict__ Wc1, const float* __restrict__ Wc2,
                             unsigned short* __restrict__ w1, unsigned short* __restrict__ w2,
                             unsigned short* __restrict__ wcls1, unsigned short* __restrict__ wcls2) {
    int i = blockIdx.x * 256 + threadIdx.x;          // 192*256 = 49152
    if (i < 16384) {
        int n = i >> 7, k = i & 127;
        float v = (k < 64) ? Wl1[k * 128 + n] : Wr1[(k - 64) * 128 + n];
        w1[i] = f2bf(v);
    } else if (i < 32768) {
        int j = i - 16384; int n = j >> 7, k = j & 127;
        float v = (n < 64) ? Wl2[k * 64 + n] : Wr2[k * 64 + (n - 64)];
        w2[j] = f2bf(v);
    } else if (i < 40960) {
        int j = i - 32768; int n = j >> 6, k = j & 63;
        wcls1[j] = f2bf(Wc1[k * 128 + n]);
    } else {
        int j = i - 40960; int n = j >> 7, k = j & 127;
        wcls2[j] = f2bf(Wc2[k * 64 + n]);
    }
}

__global__ void f32_to_bf16x4(const float* __restrict__ src, unsigned short* __restrict__ dst) {
    int i = blockIdx.x * 256 + threadIdx.x;          // 6250*256*4 = 6.4M
    float4 v = *(const float4*)(src + (long)i * 4);
    uint2 o;
    o.x = (unsigned)f2bf(v.x) | ((unsigned)f2bf(v.y) << 16);
    o.y = (unsigned)f2bf(v.z) | ((unsigned)f2bf(v.w) << 16);
    *(uint2*)(dst + (long)i * 4) = o;
}

// ---- binned CSR build ----
// Phase A: edges register-stashed (single global read pass); LDS histogram;
// ONE global atomic per (block,bucket) reserves a contiguous range; LDS-cursor scatter.
__global__ __launch_bounds__(256) void binA(const int* __restrict__ esrc,
                                            const int* __restrict__ edst,
                                            int* __restrict__ bcnt,
                                            unsigned* __restrict__ stage) {
    __shared__ int hist[NBKT];
    __shared__ int rbase[NBKT];
    int t = threadIdx.x;
    for (int i = t; i < NBKT; i += 256) hist[i] = 0;
    __syncthreads();
    int e0 = blockIdx.x * EPB;
    int e1 = e0 + EPB; if (e1 > N_EDGES) e1 = N_EDGES;
    unsigned pk[16];
    int bn[16];
#pragma unroll
    for (int j = 0; j < 16; j++) {
        int e = e0 + j * 256 + t;
        bn[j] = -1;
        if (e < N_EDGES && e < e1) {
            int d = edst[e];
            int s = esrc[e];
            int b = d >> 8;
            pk[j] = (unsigned)s | ((unsigned)(d & 255) << 24);
            bn[j] = b;
            atomicAdd(&hist[b], 1);
        }
    }
    __syncthreads();
    for (int i = t; i < NBKT; i += 256) {
        int c = hist[i];
        rbase[i] = c ? atomicAdd(&bcnt[i], c) : 0;
        hist[i] = 0;                       // becomes cursor
    }
    __syncthreads();
#pragma unroll
    for (int j = 0; j < 16; j++) {
        if (bn[j] >= 0) {
            int b = bn[j];
            int slot = rbase[b] + atomicAdd(&hist[b], 1);
            if (slot < BCAP)
                stage[(long)b * BCAP + slot] = pk[j];
        }
    }
}

// exclusive scan of 391 bucket counts; also seals off[N_NODES]
__global__ void binScan(const int* __restrict__ bcnt, int* __restrict__ bbase,
                        int* __restrict__ off) {
    __shared__ int s[512];
    int t = threadIdx.x;
    int v = (t < NBKT) ? bcnt[t] : 0;
    s[t] = v;
    __syncthreads();
    for (int st = 1; st < 512; st <<= 1) {
        int a = (t >= st) ? s[t - st] : 0;
        __syncthreads();
        s[t] += a;
        __syncthreads();
    }
    if (t < NBKT) bbase[t] = s[t] - v;
    if (t == 0) off[N_NODES] = N_EDGES;
}

// Phase B: one block per bucket; stage entries register-stashed (single read pass).
// LDS hist -> local prefix -> off[]; LDS-cursor scatter into owned contiguous region.
__global__ __launch_bounds__(256) void binB(const int* __restrict__ bcnt,
                                            const int* __restrict__ bbase,
                                            const unsigned* __restrict__ stage,
                                            int* __restrict__ off, int* __restrict__ bucket) {
    __shared__ int hist[256];
    __shared__ int scn[256];
    __shared__ int lbase[256];
    int b = blockIdx.x, t = threadIdx.x;
    int cnt = bcnt[b];
    if (cnt > BCAP) cnt = BCAP;
    int base = bbase[b];
    hist[t] = 0;
    __syncthreads();
    const unsigned* sp = stage + (long)b * BCAP;
    unsigned pk[20];
    int nv = 0;
#pragma unroll
    for (int j = 0; j < 20; j++) {
        int i = j * 256 + t;
        if (i < cnt) {
            pk[j] = sp[i];
            atomicAdd(&hist[pk[j] >> 24], 1);
            nv = j + 1;
        }
    }
    __syncthreads();
    int v = hist[t];
    scn[t] = v;
    __syncthreads();
    for (int st = 1; st < 256; st <<= 1) {
        int a = (t >= st) ? scn[t - st] : 0;
        __syncthreads();
        scn[t] += a;
        __syncthreads();
    }
    lbase[t] = scn[t] - v;
    int node = b * 256 + t;
    if (node < N_NODES) off[node] = base + lbase[t];
    hist[t] = 0;                           // reuse as running cursor
    __syncthreads();
#pragma unroll
    for (int j = 0; j < 20; j++) {
        if (j < nv) {
            unsigned p = pk[j];
            int ln = p >> 24;
            int slot = atomicAdd(&hist[ln], 1);
            bucket[base + lbase[ln] + slot] = (int)(p & 0xFFFFFFu);
        }
    }
}

// ---- bf16 gather: wave per node; lane = (neighbor g = lane>>3, channel octet c8) ----
// 32 neighbors per loop iteration: 4 independent predicated uint4 load chains per lane.
__global__ __launch_bounds__(256, 8) void gather_b(
        const unsigned short* __restrict__ y, const int* __restrict__ off,
        const int* __restrict__ bucket, unsigned short* __restrict__ outb) {
    int node = __builtin_amdgcn_readfirstlane(blockIdx.x * 4 + (threadIdx.x >> 6));
    int lane = threadIdx.x & 63;
    int g = lane >> 3, c8 = lane & 7;
    int e0 = off[node], e1 = off[node + 1];
    float a[8] = {0.f, 0.f, 0.f, 0.f, 0.f, 0.f, 0.f, 0.f};
    for (int base = e0; base < e1; base += 32) {
        uint4 v[4];
#pragma unroll
        for (int h = 0; h < 4; h++) {
            int idx = base + h * 8 + g;
            if (idx < e1) {
                int s = bucket[idx];
                v[h] = *(const uint4*)(y + (long)s * 64 + c8 * 8);
            } else {
                v[h] = (uint4){0u, 0u, 0u, 0u};
            }
        }
#pragma unroll
        for (int h = 0; h < 4; h++) {
            a[0] += bflo(v[h].x); a[1] += bfhi(v[h].x);
            a[2] += bflo(v[h].y); a[3] += bfhi(v[h].y);
            a[4] += bflo(v[h].z); a[5] += bfhi(v[h].z);
            a[6] += bflo(v[h].w); a[7] += bfhi(v[h].w);
        }
    }
#pragma unroll
    for (int j = 0; j < 8; j++) {
        a[j] += __shfl_xor(a[j], 8);
        a[j] += __shfl_xor(a[j], 16);
        a[j] += __shfl_xor(a[j], 32);
    }
    if (g == 0) {
        float sc = 1.f / fmaxf((float)(e1 - e0), 1.f);
        uint4 o;
        o.x = (unsigned)f2bf(a[0]*sc) | ((unsigned)f2bf(a[1]*sc) << 16);
        o.y = (unsigned)f2bf(a[2]*sc) | ((unsigned)f2bf(a[3]*sc) << 16);
        o.z = (unsigned)f2bf(a[4]*sc) | ((unsigned)f2bf(a[5]*sc) << 16);
        o.w = (unsigned)f2bf(a[6]*sc) | ((unsigned)f2bf(a[7]*sc) << 16);
        *(uint4*)(outb + (long)node * 64 + c8 * 8) = o;
    }
}

__global__ __launch_bounds__(256, 8) void gather_badd(
        const unsigned short* __restrict__ y, const int* __restrict__ off,
        const int* __restrict__ bucket, const float* __restrict__ add,
        float* __restrict__ out) {
    int node = __builtin_amdgcn_readfirstlane(blockIdx.x * 4 + (threadIdx.x >> 6));
    int lane = threadIdx.x & 63;
    int g = lane >> 3, c8 = lane & 7;
    int e0 = off[node], e1 = off[node + 1];
    float a[8] = {0.f, 0.f, 0.f, 0.f, 0.f, 0.f, 0.f, 0.f};
    for (int base = e0; base < e1; base += 32) {
        uint4 v[4];
#pragma unroll
        for (int h = 0; h < 4; h++) {
            int idx = base + h * 8 + g;
            if (idx < e1) {
                int s = bucket[idx];
                v[h] = *(const uint4*)(y + (long)s * 64 + c8 * 8);
            } else {
                v[h] = (uint4){0u, 0u, 0u, 0u};
            }
        }
#pragma unroll
        for (int h = 0; h < 4; h++) {
            a[0] += bflo(v[h].x); a[1] += bfhi(v[h].x);
            a[2] += bflo(v[h].y); a[3] += bfhi(v[h].y);
            a[4] += bflo(v[h].z); a[5] += bfhi(v[h].z);
            a[6] += bflo(v[h].w); a[7] += bfhi(v[h].w);
        }
    }
#pragma unroll
    for (int j = 0; j < 8; j++) {
        a[j] += __shfl_xor(a[j], 8);
        a[j] += __shfl_xor(a[j], 16);
        a[j] += __shfl_xor(a[j], 32);
    }
    if (g == 0) {
        float sc = 1.f / fmaxf((float)(e1 - e0), 1.f);
        const float4* up = (const float4*)(add + (long)node * 64 + c8 * 8);
        float4 u0 = up[0], u1 = up[1];
        float4 r0 = { a[0]*sc + u0.x, a[1]*sc + u0.y, a[2]*sc + u0.z, a[3]*sc + u0.w };
        float4 r1 = { a[4]*sc + u1.x, a[5]*sc + u1.y, a[6]*sc + u1.z, a[7]*sc + u1.w };
        float4* op = (float4*)(out + (long)node * 64 + c8 * 8);
        op[0] = r0; op[1] = r1;
    }
}

// ---- fused conv1 + conv2-transform, bf16 MFMA ----
__global__ __launch_bounds__(256, 4) void fused_conv(
        const unsigned short* __restrict__ xb, const unsigned short* __restrict__ aggb,
        const unsigned short* __restrict__ w1, const float* __restrict__ bl1,
        const unsigned short* __restrict__ w2, const float* __restrict__ bl2,
        unsigned short* __restrict__ t2b, float* __restrict__ u) {
    __shared__ __align__(16) unsigned short smemA[64 * 136];
    __shared__ __align__(16) unsigned short smemH[64 * 136];
    unsigned short* sA = smemA;
    unsigned short* sH = smemH;
    float* su = (float*)smemA;
    unsigned short* st2 = smemH;

    int t = threadIdx.x;
    int lane = t & 63;
    int wv = t >> 6;
    int q = lane >> 4, ln = lane & 15;

    long base = (long)blockIdx.x * 4096;
    long maxe = (long)N_NODES * 64 - 8;
#pragma unroll
    for (int it = 0; it < 2; it++) {
        int i = it * 256 + t;
        int m = i >> 3, k8 = (i & 7) * 8;
        long g = base + (long)m * 64 + k8;
        if (g > maxe) g = maxe;
        *(uint4*)(sA + m * 136 + k8)      = *(const uint4*)(aggb + g);
        *(uint4*)(sA + m * 136 + 64 + k8) = *(const uint4*)(xb + g);
    }
    __syncthreads();

    int n0 = wv * 32;
    float4v acc[2][4];
    {
        float b0 = bl1[n0 + ln], b1 = bl1[n0 + 16 + ln];
#pragma unroll
        for (int mi = 0; mi < 4; mi++) {
            acc[0][mi] = (float4v){b0, b0, b0, b0};
            acc[1][mi] = (float4v){b1, b1, b1, b1};
        }
    }
#pragma unroll
    for (int ks = 0; ks < 4; ks++) {
        int k0 = ks * 32 + q * 8;
        short8 bf0 = *(const short8*)(w1 + (long)(n0 + ln) * 128 + k0);
        short8 bf1 = *(const short8*)(w1 + (long)(n0 + 16 + ln) * 128 + k0);
#pragma unroll
        for (int mi = 0; mi < 4; mi++) {
            short8 af = *(const short8*)(sA + (mi * 16 + ln) * 136 + k0);
            acc[0][mi] = __builtin_amdgcn_mfma_f32_16x16x32_bf16(af, bf0, acc[0][mi], 0, 0, 0);
            acc[1][mi] = __builtin_amdgcn_mfma_f32_16x16x32_bf16(af, bf1, acc[1][mi], 0, 0, 0);
        }
    }
#pragma unroll
    for (int j = 0; j < 2; j++)
#pragma unroll
        for (int mi = 0; mi < 4; mi++) {
            int n = n0 + j * 16 + ln;
#pragma unroll
            for (int r = 0; r < 4; r++) {
                int m = mi * 16 + q * 4 + r;
                sH[m * 136 + n] = f2bf(fmaxf(acc[j][mi][r], 0.f));
            }
        }
    __syncthreads();

    float4v acc2[2][4];
    {
        float c0 = (n0 >= 64) ? bl2[n0 - 64 + ln] : 0.f;
        float c1 = (n0 >= 64) ? bl2[n0 - 48 + ln] : 0.f;
#pragma unroll
        for (int mi = 0; mi < 4; mi++) {
            acc2[0][mi] = (float4v){c0, c0, c0, c0};
            acc2[1][mi] = (float4v){c1, c1, c1, c1};
        }
    }
#pragma unroll
    for (int ks = 0; ks < 4; ks++) {
        int k0 = ks * 32 + q * 8;
        short8 bf0 = *(const short8*)(w2 + (long)(n0 + ln) * 128 + k0);
        short8 bf1 = *(const short8*)(w2 + (long)(n0 + 16 + ln) * 128 + k0);
#pragma unroll
        for (int mi = 0; mi < 4; mi++) {
            short8 af = *(const short8*)(sH + (mi * 16 + ln) * 136 + k0);
            acc2[0][mi] = __builtin_amdgcn_mfma_f32_16x16x32_bf16(af, bf0, acc2[0][mi], 0, 0, 0);
            acc2[1][mi] = __builtin_amdgcn_mfma_f32_16x16x32_bf16(af, bf1, acc2[1][mi], 0, 0, 0);
        }
    }
    __syncthreads();

#pragma unroll
    for (int j = 0; j < 2; j++)
#pragma unroll
        for (int mi = 0; mi < 4; mi++) {
            int n = n0 + j * 16 + ln;
#pragma unroll
            for (int r = 0; r < 4; r++) {
                int m = mi * 16 + q * 4 + r;
                if (wv < 2) st2[m * 72 + n] = f2bf(acc2[j][mi][r]);
                else        su[m * 68 + (n - 64)] = acc2[j][mi][r];
            }
        }
    __syncthreads();

    long lim = (long)N_NODES * 64;
    unsigned int* t2u = (unsigned int*)(t2b + base);
#pragma unroll
    for (int it = 0; it < 8; it++) {
        int i = it * 256 + t;
        long g = base + (long)i * 2;
        if (g + 1 < lim) {
            int m = (i * 2) >> 6, n = (i * 2) & 63;
            t2u[i] = (unsigned)st2[m * 72 + n] | ((unsigned)st2[m * 72 + n + 1] << 16);
        }
    }
#pragma unroll
    for (int it = 0; it < 16; it++) {
        int i = it * 256 + t;
        long g = base + i;
        if (g < lim) u[g] = su[(i >> 6) * 68 + (i & 63)];
    }
}

// ---- fused classifier head, bf16 MFMA ----
__global__ __launch_bounds__(256, 4) void fused_cls(
        const float* __restrict__ emb,
        const unsigned short* __restrict__ wcls1, const float* __restrict__ bc1,
        const unsigned short* __restrict__ wcls2, const float* __restrict__ bc2,
        const float* __restrict__ wc3, const float* __restrict__ bc3,
        float* __restrict__ probs) {
    __shared__ __align__(16) unsigned short smem[64 * 136];
    __shared__ float psum[4][64];
    unsigned short* sE = smem;
    unsigned short* sC = smem;

    int t = threadIdx.x;
    int wv = t >> 6;
    int lane = t & 63;
    int q = lane >> 4, ln = lane & 15;

    long base = (long)blockIdx.x * 4096;
    long maxe = (long)N_NODES * 64 - 4;
#pragma unroll
    for (int it = 0; it < 4; it++) {
        int i = it * 256 + t;
        int m = i >> 4, k4 = (i & 15) * 4;
        long g = base + (long)m * 64 + k4;
        if (g > maxe) g = maxe;
        float4 v = *(const float4*)(emb + g);
        uint2 o;
        o.x = (unsigned)f2bf(v.x) | ((unsigned)f2bf(v.y) << 16);
        o.y = (unsigned)f2bf(v.z) | ((unsigned)f2bf(v.w) << 16);
        *(uint2*)(sE + m * 72 + k4) = o;
    }
    __syncthreads();

    int n0 = wv * 32;
    float4v acc[2][4];
    {
        float b0 = bc1[n0 + ln], b1 = bc1[n0 + 16 + ln];
#pragma unroll
        for (int mi = 0; mi < 4; mi++) {
            acc[0][mi] = (float4v){b0, b0, b0, b0};
            acc[1][mi] = (float4v){b1, b1, b1, b1};
        }
    }
#pragma unroll
    for (int ks = 0; ks < 2; ks++) {
        int k0 = ks * 32 + q * 8;
        short8 bf0 = *(const short8*)(wcls1 + (long)(n0 + ln) * 64 + k0);
        short8 bf1 = *(const short8*)(wcls1 + (long)(n0 + 16 + ln) * 64 + k0);
#pragma unroll
        for (int mi = 0; mi < 4; mi++) {
            short8 af = *(const short8*)(sE + (mi * 16 + ln) * 72 + k0);
            acc[0][mi] = __builtin_amdgcn_mfma_f32_16x16x32_bf16(af, bf0, acc[0][mi], 0, 0, 0);
            acc[1][mi] = __builtin_amdgcn_mfma_f32_16x16x32_bf16(af, bf1, acc[1][mi], 0, 0, 0);
        }
    }
    __syncthreads();
#pragma unroll
    for (int j = 0; j < 2; j++)
#pragma unroll
        for (int mi = 0; mi < 4; mi++) {
            int n = n0 + j * 16 + ln;
#pragma unroll
            for (int r = 0; r < 4; r++) {
                int m = mi * 16 + q * 4 + r;
                sC[m * 136 + n] = f2bf(fmaxf(acc[j][mi][r], 0.f));
            }
        }
    __syncthreads();

    int n0c = wv * 16;
    float4v acc3[4];
    {
        float b = bc2[n0c + ln];
#pragma unroll
        for (int mi = 0; mi < 4; mi++) acc3[mi] = (float4v){b, b, b, b};
    }
#pragma unroll
    for (int ks = 0; ks < 4; ks++) {
        int k0 = ks * 32 + q * 8;
        short8 bf0 = *(const short8*)(wcls2 + (long)(n0c + ln) * 128 + k0);
#pragma unroll
        for (int mi = 0; mi < 4; mi++) {
            short8 af = *(const short8*)(sC + (mi * 16 + ln) * 136 + k0);
            acc3[mi] = __builtin_amdgcn_mfma_f32_16x16x32_bf16(af, bf0, acc3[mi], 0, 0, 0);
        }
    }
    float w3 = wc3[n0c + ln];
#pragma unroll
    for (int mi = 0; mi < 4; mi++)
#pragma unroll
        for (int r = 0; r < 4; r++) {
            float v = fmaxf(acc3[mi][r], 0.f) * w3;
            v += __shfl_xor(v, 1);
            v += __shfl_xor(v, 2);
            v += __shfl_xor(v, 4);
            v += __shfl_xor(v, 8);
            if (ln == 0) psum[wv][mi * 16 + q * 4 + r] = v;
        }
    __syncthreads();
    if (t < 64) {
        int node = blockIdx.x * 64 + t;
        if (node < N_NODES) {
            float tot = psum[0][t] + psum[1][t] + psum[2][t] + psum[3][t] + bc3[0];
            probs[node] = 1.f / (1.f + expf(-tot));
        }
    }
}

extern "C" void kernel_launch(void* const* d_in, const int* in_sizes, int n_in,
                              void* d_out, int out_size, void* d_ws, size_t ws_size,
                              hipStream_t stream) {
    const float* x   = (const float*)d_in[0];
    const int*   ei  = (const int*)d_in[1];
    const float* Wl1 = (const float*)d_in[2];
    const float* bl1 = (const float*)d_in[3];
    const float* Wr1 = (const float*)d_in[4];
    const float* Wl2 = (const float*)d_in[5];
    const float* bl2 = (const float*)d_in[6];
    const float* Wr2 = (const float*)d_in[7];
    const float* Wc1 = (const float*)d_in[8];
    const float* bc1 = (const float*)d_in[9];
    const float* Wc2 = (const float*)d_in[10];
    const float* bc2 = (const float*)d_in[11];
    const float* Wc3 = (const float*)d_in[12];
    const float* bc3 = (const float*)d_in[13];

    float* out = (float*)d_out;

    // ---- ws carve ----
    int* iw     = (int*)d_ws;
    int* bcnt   = iw;                       // 392 (zeroed)
    int* bbase  = iw + 392;                 // 392 (+pad to 1024 total)
    int* off    = iw + 1024;                // N_NODES+1, padded to 100352
    int* bucket = iw + 1024 + 100352;       // N_EDGES
    unsigned* stage = (unsigned*)(iw + 1024 + 100352 + N_EDGES);  // NBKT*BCAP
    size_t ioff = (size_t)(1024 + 100352 + N_EDGES + (long)NBKT * BCAP) * 4;

    char* wsb = (char*)d_ws;
    unsigned short* xb    = (unsigned short*)(wsb + ioff);                  // 12.8 MB
    unsigned short* agg1b = xb + 6400000L;                                  // 12.8 MB
    unsigned short* t2b   = agg1b + 6400000L;                               // 12.8 MB
    float*          u     = (float*)(wsb + ioff + 3L * 12800000L);          // 25.6 MB
    unsigned short* w1    = (unsigned short*)(wsb + ioff + 3L * 12800000L + 25600000L);
    unsigned short* w2    = w1 + 16384;
    unsigned short* wcls1 = w2 + 16384;
    unsigned short* wcls2 = wcls1 + 8192;

    float* emb   = out;                     // [100000 x 64]
    float* probs = out + 6400000L;          // [100000]

    const int* esrc = ei;
    const int* edst = ei + N_EDGES;

    hipMemsetAsync(bcnt, 0, 1024 * sizeof(int), stream);

    prep_weights<<<192, 256, 0, stream>>>(Wl1, Wr1, Wl2, Wr2, Wc1, Wc2,
                                          w1, w2, wcls1, wcls2);
    f32_to_bf16x4<<<6250, 256, 0, stream>>>(x, xb);

    binA<<<NBLKA, 256, 0, stream>>>(esrc, edst, bcnt, stage);
    binScan<<<1, 512, 0, stream>>>(bcnt, bbase, off);
    binB<<<NBKT, 256, 0, stream>>>(bcnt, bbase, stage, off, bucket);

    gather_b<<<25000, 256, 0, stream>>>(xb, off, bucket, agg1b);
    fused_conv<<<1563, 256, 0, stream>>>(xb, agg1b, w1, bl1, w2, bl2, t2b, u);
    gather_badd<<<25000, 256, 0, stream>>>(t2b, off, bucket, u, emb);
    fused_cls<<<1563, 256, 0, stream>>>(emb, wcls1, bc1, wcls2, bc2, Wc3, bc3, probs);
}